// Round 14
// baseline (722.516 us; speedup 1.0000x reference)
//
#include <hip/hip_runtime.h>

typedef unsigned short u16;
typedef __attribute__((ext_vector_type(4))) float f4;
typedef __attribute__((ext_vector_type(8))) short s8v;      // bf16x8 MFMA operand
typedef __attribute__((ext_vector_type(8))) unsigned short u16x8;
typedef __attribute__((ext_vector_type(4))) unsigned short u16x4;

#define B_   4
#define S_   4096
#define D_   2048
#define M_   (B_ * S_)     // 16384
#define K_   D_            // 2048
#define N3_  (3 * D_)      // 6144
#define CCH  128           // scan chunks
#define LCH  32            // chunk length
#define SCH  8             // superchunks
#define SCL  16            // chunks per superchunk
#define NKT  64            // K_/32 K-tiles

__device__ __forceinline__ u16 f2bf(float f) {
  unsigned u = __float_as_uint(f);
  u += 0x7FFF + ((u >> 16) & 1);   // RNE
  return (u16)(u >> 16);
}
__device__ __forceinline__ float bf2f(u16 h) {
  return __uint_as_float(((unsigned)h) << 16);
}
__device__ __forceinline__ float sigm(float z) {
  return 1.0f / (1.0f + __expf(-z));
}

// ---------------- fp32 -> bf16 elementwise (x), grid-stride ----------------
__global__ void k_cvt(const float* __restrict__ src, u16* __restrict__ dst, int n4) {
  for (int i = blockIdx.x * 256 + threadIdx.x; i < n4; i += 2048 * 256) {
    f4 v = *(const f4*)(src + (size_t)i * 4);
    u16x4 o;
    o[0] = f2bf(v[0]); o[1] = f2bf(v[1]); o[2] = f2bf(v[2]); o[3] = f2bf(v[3]);
    *(u16x4*)(dst + (size_t)i * 4) = o;
  }
}

// ---------------- fp32 [2048][2048] -> bf16 transpose, all 4 weights ----------------
__global__ void k_tcvt4(const float* __restrict__ W_in, const float* __restrict__ W_dec,
                        const float* __restrict__ W_gate, const float* __restrict__ W_out,
                        u16* __restrict__ w3t, u16* __restrict__ wot) {
  __shared__ float tile[32][33];
  const float* src = (blockIdx.z == 0) ? W_in : (blockIdx.z == 1) ? W_dec
                    : (blockIdx.z == 2) ? W_gate : W_out;
  u16* dst = (blockIdx.z < 3) ? (w3t + (size_t)blockIdx.z * 2048 * 2048) : wot;
  int tx = threadIdx.x & 31, ty = threadIdx.x >> 5;
  int c0 = blockIdx.x * 32, r0 = blockIdx.y * 32;
#pragma unroll
  for (int j = 0; j < 32; j += 8)
    tile[ty + j][tx] = src[(size_t)(r0 + ty + j) * 2048 + c0 + tx];
  __syncthreads();
#pragma unroll
  for (int j = 0; j < 32; j += 8)
    dst[(size_t)(c0 + ty + j) * 2048 + r0 + tx] = f2bf(tile[tx][ty + j]);
}

// ---------------- 128x256 / BK=32 bf16 GEMM, 2 blocks/CU (m114 overlap) ------
// LDS 48 KiB: A[2] 64pr x 64, B[2] 128pr x 64 (u16) — BK=32 rows PAIR-PACKED
// into 128 B physical rows (row 2r,2r+1 share packed row pr=r; logical slot
// s_log = (row&1)*4 + k8; physical slot = s_log ^ (pr&7)) so bank geometry
// equals the proven BK=64 layout (0 conflicts). Staging: linear-dest
// global_load_lds, involution pre-applied to the per-lane GLOBAL offset.
// Schedule (2 phases/K-tile): h0 stages A(t+1)->nxt; h1 stages B(t+2)x2->cur,
// vmcnt(2), reads next tile's A (readahead) and B (tail). Every stage target
// is >=1 barrier + 1 full phase after its last read; every first-read is
// vmcnt-covered (ledger in round notes). 8 waves, 64x64/wave, acc=64 VGPR ->
// launch_bounds(512,4) gives 2 blocks/CU: sibling block's MFMAs fill barrier
// stalls (m114 implicit wave-level overlap).
__global__ void __launch_bounds__(512, 4)
k_gemm128(const u16* __restrict__ A, const u16* __restrict__ BT, int N, int mode,
          u16* __restrict__ o_inp, u16* __restrict__ o_dec, u16* __restrict__ o_gate,
          const float* __restrict__ b_in, const float* __restrict__ b_dec,
          const float* __restrict__ b_gate, const float* __restrict__ dbias,
          float* __restrict__ o_f, const float* __restrict__ b_out) {
  extern __shared__ u16 smem[];
  u16* const As0 = smem;                // 4096 elems
  u16* const As1 = smem + 4096;
  u16* const Bs0 = smem + 8192;         // 8192 elems
  u16* const Bs1 = smem + 16384;

  // XCD cluster map: xcd owns 16 m-bands; co-resident blocks share panels.
  const int bid = blockIdx.x;
  const int xcd = bid & 7, j = bid >> 3;
  const int tile_m = ((xcd << 4) + (j & 15)) << 7;
  const int tile_n = (j >> 4) << 8;

  const int tid = threadIdx.x;
  const int wave = tid >> 6, lane = tid & 63;
  const int wm = (wave >> 2) << 6;              // 0 or 64
  const int wn = (wave & 3) << 6;               // 0,64,128,192
  const int l15 = lane & 15, lhi = lane >> 4;

  // staging lane constants (packed-pair involution applied to global offset)
  const int slog = (tid & 7) ^ ((tid >> 3) & 7);
  const int gl = ((((tid >> 3) << 1) + (slog >> 2)) * K_) + ((slog & 3) << 3);
  const int ldst = (wave << 9);                 // + c*4096 for B chunk 1

  // fragment read pointers (compile-time mf/nf steps of 512 elems)
  const int phys = (((l15 & 1) << 2) + lhi) ^ ((l15 >> 1) & 7);
  const int rbase = ((l15 >> 1) << 6) + (phys << 3);
  const u16* const apb[2] = { As0 + (wm << 5) + rbase, As1 + (wm << 5) + rbase };
  const u16* const bpb[2] = { Bs0 + (wn << 5) + rbase, Bs1 + (wn << 5) + rbase };

  f4 acc[4][4];
#pragma unroll
  for (int m = 0; m < 4; ++m)
#pragma unroll
    for (int n = 0; n < 4; ++n)
#pragma unroll
      for (int r = 0; r < 4; ++r) acc[m][n][r] = 0.0f;

  s8v afr2[2][2];   // [set][i]: set0 = mf0,1 ; set1 = mf2,3
  s8v bfr[4];

  auto STAGE = [&](const u16* __restrict__ G, int grow0, u16* L, int c, int k0) {
    const u16* src = G + (size_t)(grow0 + (c << 7)) * K_ + k0;   // uniform (saddr)
    __builtin_amdgcn_global_load_lds(
        (const __attribute__((address_space(1))) unsigned int*)(src + gl),
        (__attribute__((address_space(3))) unsigned int*)(L + (c << 12) + ldst),
        16, 0, 0);
  };

  // ---- prologue: tiles 0 and 1 fully (3 loads each) ----
  STAGE(A, tile_m, As0, 0, 0);
  STAGE(BT, tile_n, Bs0, 0, 0); STAGE(BT, tile_n, Bs0, 1, 0);
  STAGE(A, tile_m, As1, 0, 32);
  STAGE(BT, tile_n, Bs1, 0, 32); STAGE(BT, tile_n, Bs1, 1, 32);
  asm volatile("s_waitcnt vmcnt(3)" ::: "memory");   // tile 0's 3 loads retired
  __builtin_amdgcn_s_barrier();
#pragma unroll
  for (int i = 0; i < 2; ++i) afr2[0][i] = *(const s8v*)(apb[0] + i * 512);
#pragma unroll
  for (int nf = 0; nf < 4; ++nf) bfr[nf] = *(const s8v*)(bpb[0] + nf * 512);

#pragma unroll 1
  for (int it = 0; it < NKT / 2; ++it) {
    const int t = it << 1;
#pragma unroll
    for (int half = 0; half < 2; ++half) {       // half 0: cur=buf0; half 1: cur=buf1
      const int tt = t + half;
      const int cur = half, nxt = half ^ 1;
      u16* const Acur = half ? As1 : As0;  (void)Acur;
      u16* const Anxt = half ? As0 : As1;
      u16* const Bcur = half ? Bs1 : Bs0;

      // ---- h0: stage A(tt+1) -> nxt ; read A cur mf2,3 ; MFMA mf0,1 ----
      STAGE(A, tile_m, Anxt, 0, ((tt + 1) & (NKT - 1)) << 5);
      __builtin_amdgcn_s_barrier();
#pragma unroll
      for (int i = 0; i < 2; ++i) afr2[1][i] = *(const s8v*)(apb[cur] + (2 + i) * 512);
      __builtin_amdgcn_s_setprio(1);
#pragma unroll
      for (int i = 0; i < 2; ++i)
#pragma unroll
        for (int nf = 0; nf < 4; ++nf)
          acc[i][nf] = __builtin_amdgcn_mfma_f32_16x16x32_bf16(afr2[0][i], bfr[nf], acc[i][nf], 0, 0, 0);
      __builtin_amdgcn_s_setprio(0);

      // ---- h1: stage B(tt+2)x2 -> cur ; vmcnt(2) ; read A nxt mf0,1 ; MFMA mf2,3 ; tail B nxt ----
      {
        const int k2 = ((tt + 2) & (NKT - 1)) << 5;
        STAGE(BT, tile_n, Bcur, 0, k2); STAGE(BT, tile_n, Bcur, 1, k2);
      }
      asm volatile("s_waitcnt vmcnt(2)" ::: "memory");
      __builtin_amdgcn_sched_barrier(0);
      __builtin_amdgcn_s_barrier();
#pragma unroll
      for (int i = 0; i < 2; ++i) afr2[0][i] = *(const s8v*)(apb[nxt] + i * 512);
      __builtin_amdgcn_s_setprio(1);
#pragma unroll
      for (int i = 0; i < 2; ++i)
#pragma unroll
        for (int nf = 0; nf < 4; ++nf)
          acc[2 + i][nf] = __builtin_amdgcn_mfma_f32_16x16x32_bf16(afr2[1][i], bfr[nf], acc[2 + i][nf], 0, 0, 0);
      __builtin_amdgcn_s_setprio(0);
#pragma unroll
      for (int nf = 0; nf < 4; ++nf) bfr[nf] = *(const s8v*)(bpb[nxt] + nf * 512);
    }
  }

  // ---- epilogue: drain in-flight gload_lds, then reuse LDS (sweeps) ----
  asm volatile("s_waitcnt vmcnt(0)" ::: "memory");
  __builtin_amdgcn_s_barrier();

  if (mode == 0) {
    const int selb = tile_n >> 11;
    const int dbase = tile_n & 2047;
    u16* const dst = (selb == 0) ? o_inp : (selb == 1) ? o_dec : o_gate;
    float bias[4];
#pragma unroll
    for (int nf = 0; nf < 4; ++nf) {
      int d = dbase + wn + (nf << 4) + l15;
      bias[nf] = (selb == 0) ? b_in[d] : (selb == 1) ? (b_dec[d] + dbias[d]) : b_gate[d];
    }
    const int rr = tid >> 5, sl = tid & 31;
#pragma unroll
    for (int sw = 0; sw < 2; ++sw) {             // 64-row sweeps (32 KiB)
      if ((wm >> 6) == sw) {
#pragma unroll
        for (int mf = 0; mf < 4; ++mf)
#pragma unroll
          for (int nf = 0; nf < 4; ++nf)
#pragma unroll
            for (int r = 0; r < 4; ++r) {
              int lrow = (mf << 4) + (lhi << 2) + r;          // 0..63
              int lcol = wn + (nf << 4) + l15;
              float z = acc[mf][nf][r] + bias[nf];
              float v = (selb == 0) ? z * sigm(z) : sigm(z);
              smem[(lrow << 8) + (((lcol >> 3) ^ (lrow & 7)) << 3) + (lcol & 7)] = f2bf(v);
            }
      }
      asm volatile("s_waitcnt lgkmcnt(0)" ::: "memory");
      __builtin_amdgcn_s_barrier();
#pragma unroll
      for (int pass = 0; pass < 4; ++pass) {
        int row = (pass << 4) + rr;                           // 0..63
        u16x8 v = *(const u16x8*)(smem + (row << 8) + ((sl ^ (row & 7)) << 3));
        *(u16x8*)(dst + (size_t)(tile_m + (sw << 6) + row) * D_ + dbase + (sl << 3)) = v;
      }
      asm volatile("s_waitcnt lgkmcnt(0)" ::: "memory");
      __builtin_amdgcn_s_barrier();
    }
  } else {
    float* const Tf = (float*)smem;
    f4 bo = *(const f4*)(b_out + tile_n + (lane << 2));
#pragma unroll
    for (int sw = 0; sw < 4; ++sw) {             // 32-row sweeps (32 KiB)
      if ((wm >> 6) == (sw >> 1)) {
        const int mb = (sw & 1) << 1;
#pragma unroll
        for (int mm = 0; mm < 2; ++mm)
#pragma unroll
          for (int nf = 0; nf < 4; ++nf)
#pragma unroll
            for (int r = 0; r < 4; ++r) {
              int lrow = (mm << 4) + (lhi << 2) + r;          // 0..31
              int lcol = wn + (nf << 4) + l15;
              Tf[(lrow << 8) + (((lcol >> 2) ^ (lrow & 7)) << 2) + (lcol & 3)] = acc[mb + mm][nf][r];
            }
      }
      asm volatile("s_waitcnt lgkmcnt(0)" ::: "memory");
      __builtin_amdgcn_s_barrier();
#pragma unroll
      for (int pass = 0; pass < 4; ++pass) {
        int lrow = (pass << 3) + wave;                        // 0..31
        f4 v = *(const f4*)(Tf + (lrow << 8) + ((lane ^ (lrow & 7)) << 2));
        v[0] += bo[0]; v[1] += bo[1]; v[2] += bo[2]; v[3] += bo[3];
        *(f4*)(o_f + (size_t)(tile_m + (sw << 5) + lrow) * D_ + tile_n + (lane << 2)) = v;
      }
      asm volatile("s_waitcnt lgkmcnt(0)" ::: "memory");
      __builtin_amdgcn_s_barrier();
    }
  }
}

// ---------------- scan pass 1: per-chunk (prod-decay, zero-init state) ----------------
__global__ void k_scan1(const u16* __restrict__ dec, const u16* __restrict__ inp,
                        float* __restrict__ chA, float* __restrict__ chB) {
  int b = blockIdx.x / CCH, c = blockIdx.x % CCH;
  int d0 = threadIdx.x * 8;
  const u16* dp = dec + ((size_t)b * S_ + c * LCH) * D_ + d0;
  const u16* ip = inp + ((size_t)b * S_ + c * LCH) * D_ + d0;
  float Aa[8], st[8];
#pragma unroll
  for (int i = 0; i < 8; ++i) { Aa[i] = 1.0f; st[i] = 0.0f; }
#pragma unroll 4
  for (int j = 0; j < LCH; ++j) {
    u16x8 dv = *(const u16x8*)(dp + (size_t)j * D_);
    u16x8 iv = *(const u16x8*)(ip + (size_t)j * D_);
#pragma unroll
    for (int i = 0; i < 8; ++i) {
      float dd = bf2f(dv[i]), ii = bf2f(iv[i]);
      Aa[i] *= dd;
      st[i] = dd * st[i] + (1.0f - dd) * ii;
    }
  }
  size_t o = ((size_t)b * CCH + c) * D_ + d0;
#pragma unroll
  for (int i = 0; i < 8; ++i) { chA[o + i] = Aa[i]; chB[o + i] = st[i]; }
}

// ---------------- scan pass 2a: compose 16 chunks -> superchunk ----------------
__global__ void k_scan2a(const float* __restrict__ chA, const float* __restrict__ chB,
                         float* __restrict__ sA, float* __restrict__ sB) {
  int gid = blockIdx.x * 256 + threadIdx.x;
  int d = gid & (D_ - 1);
  int s = (gid >> 11) & (SCH - 1);
  int b = gid >> 14;
  float Aa = 1.0f, Bb = 0.0f;
  for (int c = 0; c < SCL; ++c) {
    size_t o = ((size_t)b * CCH + s * SCL + c) * D_ + d;
    float a = chA[o], bb = chB[o];
    Aa *= a;
    Bb = a * Bb + bb;
  }
  size_t so = ((size_t)b * SCH + s) * D_ + d;
  sA[so] = Aa; sB[so] = Bb;
}

// ---------------- scan pass 2b: prefix over 8 superchunks ----------------
__global__ void k_scan2b(const float* __restrict__ sA, const float* __restrict__ sB,
                         float* __restrict__ sI) {
  int gid = blockIdx.x * 256 + threadIdx.x;      // 8192
  int d = gid & (D_ - 1);
  int b = gid >> 11;
  float st = 0.0f;
  for (int s = 0; s < SCH; ++s) {
    size_t o = ((size_t)b * SCH + s) * D_ + d;
    sI[o] = st;
    st = sA[o] * st + sB[o];
  }
}

// ---------------- scan pass 2c: within-super prefix -> ini ----------------
__global__ void k_scan2c(const float* __restrict__ chA, const float* __restrict__ chB,
                         const float* __restrict__ sI, float* __restrict__ ini) {
  int gid = blockIdx.x * 256 + threadIdx.x;      // 65536
  int d = gid & (D_ - 1);
  int s = (gid >> 11) & (SCH - 1);
  int b = gid >> 14;
  float st = sI[((size_t)b * SCH + s) * D_ + d];
  for (int c = 0; c < SCL; ++c) {
    size_t o = ((size_t)b * CCH + s * SCL + c) * D_ + d;
    ini[o] = st;
    st = chA[o] * st + chB[o];
  }
}

// ---------------- scan pass 3: apply with true init, write y = gate*state ----------------
__global__ void k_scan3(const u16* __restrict__ dec, const u16* __restrict__ inp,
                        const u16* __restrict__ gat, const float* __restrict__ ini,
                        u16* __restrict__ y) {
  int b = blockIdx.x / CCH, c = blockIdx.x % CCH;
  int d0 = threadIdx.x * 8;
  size_t ib = ((size_t)b * CCH + c) * D_ + d0;
  float st[8];
#pragma unroll
  for (int i = 0; i < 8; ++i) st[i] = ini[ib + i];
  size_t base = ((size_t)b * S_ + c * LCH) * D_ + d0;
#pragma unroll 4
  for (int j = 0; j < LCH; ++j) {
    size_t o = base + (size_t)j * D_;
    u16x8 dv = *(const u16x8*)(dec + o);
    u16x8 iv = *(const u16x8*)(inp + o);
    u16x8 gv = *(const u16x8*)(gat + o);
    u16x8 yv;
#pragma unroll
    for (int i = 0; i < 8; ++i) {
      float dd = bf2f(dv[i]), ii = bf2f(iv[i]);
      st[i] = dd * st[i] + (1.0f - dd) * ii;
      yv[i] = f2bf(bf2f(gv[i]) * st[i]);
    }
    *(u16x8*)(y + o) = yv;
  }
}

extern "C" void kernel_launch(void* const* d_in, const int* in_sizes, int n_in,
                              void* d_out, int out_size, void* d_ws, size_t ws_size,
                              hipStream_t stream) {
  (void)in_sizes; (void)n_in; (void)out_size; (void)ws_size;
  const float* x      = (const float*)d_in[0];
  const float* W_in   = (const float*)d_in[1];
  const float* b_in   = (const float*)d_in[2];
  const float* W_dec  = (const float*)d_in[3];
  const float* b_dec  = (const float*)d_in[4];
  const float* W_gate = (const float*)d_in[5];
  const float* b_gate = (const float*)d_in[6];
  const float* W_out  = (const float*)d_in[7];
  const float* b_out  = (const float*)d_in[8];
  const float* dbias  = (const float*)d_in[9];
  float* out = (float*)d_out;

  char* ws = (char*)d_ws;
  u16*   xb  = (u16*)(ws);                    // 64 MiB (reused as y)
  u16*   w3t = (u16*)(ws + 67108864ull);      // 24 MiB
  u16*   wot = (u16*)(ws + 92274688ull);      //  8 MiB
  u16*   inp = (u16*)(ws + 100663296ull);     // 64 MiB
  u16*   dec = (u16*)(ws + 167772160ull);     // 64 MiB
  u16*   gat = (u16*)(ws + 234881024ull);     // 64 MiB
  float* chA = (float*)(ws + 301989888ull);   // 4 MiB
  float* chB = (float*)(ws + 306184192ull);   // 4 MiB
  float* ini = (float*)(ws + 310378496ull);   // 4 MiB
  float* sA  = (float*)(ws + 314572800ull);   // 256 KiB
  float* sB  = (float*)(ws + 314834944ull);   // 256 KiB
  float* sI  = (float*)(ws + 315097088ull);   // 256 KiB
  u16*   y   = xb;

  hipFuncSetAttribute((const void*)k_gemm128,
                      hipFuncAttributeMaxDynamicSharedMemorySize, 49152);

  k_cvt<<<2048, 256, 0, stream>>>(x, xb, 8388608);
  k_tcvt4<<<dim3(64, 64, 4), 256, 0, stream>>>(W_in, W_dec, W_gate, W_out, w3t, wot);

  k_gemm128<<<(M_ / 128) * (N3_ / 256), 512, 49152, stream>>>(
      xb, w3t, N3_, 0, inp, dec, gat, b_in, b_dec, b_gate, dbias, nullptr, nullptr);

  k_scan1<<<B_ * CCH, 256, 0, stream>>>(dec, inp, chA, chB);
  k_scan2a<<<256, 256, 0, stream>>>(chA, chB, sA, sB);
  k_scan2b<<<32, 256, 0, stream>>>(sA, sB, sI);
  k_scan2c<<<256, 256, 0, stream>>>(chA, chB, sI, ini);
  k_scan3<<<B_ * CCH, 256, 0, stream>>>(dec, inp, gat, ini, y);

  k_gemm128<<<(M_ / 128) * (D_ / 256), 512, 49152, stream>>>(
      y, wot, D_, 1, nullptr, nullptr, nullptr, nullptr, nullptr, nullptr, nullptr,
      out, b_out);
}

// Round 15
// 631.256 us; speedup vs baseline: 1.1446x; 1.1446x over previous
//
#include <hip/hip_runtime.h>

typedef unsigned short u16;
typedef __attribute__((ext_vector_type(4))) float f4;
typedef __attribute__((ext_vector_type(8))) short s8v;      // bf16x8 MFMA operand
typedef __attribute__((ext_vector_type(8))) unsigned short u16x8;
typedef __attribute__((ext_vector_type(4))) unsigned short u16x4;

#define B_   4
#define S_   4096
#define D_   2048
#define M_   (B_ * S_)     // 16384
#define K_   D_            // 2048
#define N3_  (3 * D_)      // 6144
#define CCH  128           // scan chunks
#define LCH  32            // chunk length
#define NTK  32            // K_ / 64 K-tiles
#define SCH  8             // superchunks
#define SCL  16            // chunks per superchunk (SCH*SCL == CCH)

__device__ __forceinline__ u16 f2bf(float f) {
  unsigned u = __float_as_uint(f);
  u += 0x7FFF + ((u >> 16) & 1);   // RNE
  return (u16)(u >> 16);
}
__device__ __forceinline__ float bf2f(u16 h) {
  return __uint_as_float(((unsigned)h) << 16);
}
__device__ __forceinline__ float sigm(float z) {
  return 1.0f / (1.0f + __expf(-z));
}

// ---------------- fp32 -> bf16 elementwise (x), grid-stride ----------------
__global__ void k_cvt(const float* __restrict__ src, u16* __restrict__ dst, int n4) {
  for (int i = blockIdx.x * 256 + threadIdx.x; i < n4; i += 2048 * 256) {
    f4 v = *(const f4*)(src + (size_t)i * 4);
    u16x4 o;
    o[0] = f2bf(v[0]); o[1] = f2bf(v[1]); o[2] = f2bf(v[2]); o[3] = f2bf(v[3]);
    *(u16x4*)(dst + (size_t)i * 4) = o;
  }
}

// ---------------- fp32 [2048][2048] -> bf16 transpose, all 4 weights ----------------
__global__ void k_tcvt4(const float* __restrict__ W_in, const float* __restrict__ W_dec,
                        const float* __restrict__ W_gate, const float* __restrict__ W_out,
                        u16* __restrict__ w3t, u16* __restrict__ wot) {
  __shared__ float tile[32][33];
  const float* src = (blockIdx.z == 0) ? W_in : (blockIdx.z == 1) ? W_dec
                    : (blockIdx.z == 2) ? W_gate : W_out;
  u16* dst = (blockIdx.z < 3) ? (w3t + (size_t)blockIdx.z * 2048 * 2048) : wot;
  int tx = threadIdx.x & 31, ty = threadIdx.x >> 5;
  int c0 = blockIdx.x * 32, r0 = blockIdx.y * 32;
#pragma unroll
  for (int j = 0; j < 32; j += 8)
    tile[ty + j][tx] = src[(size_t)(r0 + ty + j) * 2048 + c0 + tx];
  __syncthreads();
#pragma unroll
  for (int j = 0; j < 32; j += 8)
    dst[(size_t)(c0 + ty + j) * 2048 + r0 + tx] = f2bf(tile[tx][ty + j]);
}

// ---------------- 256x256 8-phase bf16 GEMM, 16x16x32 MFMA, 1 barrier/phase --
// Proven R12/R13 kernel (unchanged): conflict-free 16x16 fragments, XOR slot
// swizzle via pre-swizzled global source, A read-ahead one phase, B refresh at
// q3 tails, vmcnt(6) at q3 only, XCD cluster map, single barrier per phase.
__global__ void __launch_bounds__(512, 2)
k_gemm256(const u16* __restrict__ A, const u16* __restrict__ BT, int N, int mode,
          u16* __restrict__ o_inp, u16* __restrict__ o_dec, u16* __restrict__ o_gate,
          const float* __restrict__ b_in, const float* __restrict__ b_dec,
          const float* __restrict__ b_gate, const float* __restrict__ dbias,
          float* __restrict__ o_f, const float* __restrict__ b_out) {
  extern __shared__ u16 smem[];
  u16* const Asb[2] = { smem,         smem + 16384 };
  u16* const Bsb[2] = { smem + 32768, smem + 49152 };

  const int bid = blockIdx.x;
  const int xcd = bid & 7, j = bid >> 3;
  const int nsb = j >> 6;
  const int rj = j & 63;
  const int mm = rj >> 3, nn = rj & 7;
  const int tile_m = ((xcd << 3) + mm) << 8;
  const int tile_n = ((nsb << 3) + nn) << 8;

  const int tid = threadIdx.x;
  const int wave = tid >> 6, lane = tid & 63;
  const int wm = (wave >> 2) << 7;              // 0 or 128
  const int wn = (wave & 3) << 6;               // 0,64,128,192
  const int l15 = lane & 15, lhi = lane >> 4;
  const int srow = tid >> 3, sslot = tid & 7;   // staging: row-in-chunk, 16B slot

  f4 acc[8][4];
#pragma unroll
  for (int m = 0; m < 8; ++m)
#pragma unroll
    for (int n = 0; n < 4; ++n)
#pragma unroll
      for (int r = 0; r < 4; ++r) acc[m][n][r] = 0.0f;

  s8v afr2[2][2][2];   // A fragments [set][mi][kk]
  s8v bfr[2][4];       // B fragments [kk][n]

  const int swz = l15 & 7;
  const u16* ap[2][2];
  const u16* bp[2][2];
#pragma unroll
  for (int b = 0; b < 2; ++b)
#pragma unroll
    for (int kk = 0; kk < 2; ++kk) {
      const int so = ((((kk << 2) + lhi) ^ swz) << 3);
      ap[b][kk] = Asb[b] + ((wm + l15) << 6) + so;
      bp[b][kk] = Bsb[b] + ((wn + l15) << 6) + so;
    }
  const int gl = srow * K_ + ((sslot ^ (srow & 7)) << 3);

  auto STAGE = [&](const u16* __restrict__ G, int grow0, u16* L, int c, int k0) {
    const u16* src = G + (size_t)(grow0 + (c << 6)) * K_ + k0;   // uniform (saddr)
    __builtin_amdgcn_global_load_lds(
        (const __attribute__((address_space(1))) unsigned int*)(src + gl),
        (__attribute__((address_space(3))) unsigned int*)(L + (((c << 6) + (wave << 3)) << 6)),
        16, 0, 0);
  };

  // ---- prologue: tile 0 fully (8 chunks) + tile 1 partial (B all, A chunks 0,2)
#pragma unroll
  for (int c = 0; c < 4; ++c) STAGE(A, tile_m, Asb[0], c, 0);
#pragma unroll
  for (int c = 0; c < 4; ++c) STAGE(BT, tile_n, Bsb[0], c, 0);
#pragma unroll
  for (int c = 0; c < 4; ++c) STAGE(BT, tile_n, Bsb[1], c, 64);
  STAGE(A, tile_m, Asb[1], 0, 64);
  STAGE(A, tile_m, Asb[1], 2, 64);
  asm volatile("s_waitcnt vmcnt(6)" ::: "memory");   // tile 0's 8 loads retired
  __builtin_amdgcn_s_barrier();

#pragma unroll
  for (int kk = 0; kk < 2; ++kk)
#pragma unroll
    for (int mi = 0; mi < 2; ++mi)
      afr2[0][mi][kk] = *(const s8v*)(ap[0][kk] + (mi << 10));
#pragma unroll
  for (int kk = 0; kk < 2; ++kk)
#pragma unroll
    for (int n = 0; n < 4; ++n)
      bfr[kk][n] = *(const s8v*)(bp[0][kk] + (n << 10));

#pragma unroll 1
  for (int it = 0; it < NTK / 2; ++it) {
    const int t0 = it << 1;
#pragma unroll
    for (int p = 0; p < 8; ++p) {
      const int toff[8] = {1, 2, 2, 2, 2, 3, 3, 3};   // staged tile = t0 + toff
      const int sopA[8] = {1, 0, 0, 1, 1, 0, 0, 1};   // 1 = stage A chunks, 0 = B
      const int sc0[8]  = {1, 0, 2, 0, 1, 0, 2, 0};
      const int sc1f[8] = {3, 1, 3, 2, 3, 1, 3, 2};
      const int q = p & 3;

      {
        const int st = (t0 + toff[p]) & (NTK - 1);   // wraps harmlessly on last iter
        const int k0s = st << 6;
        u16* const Ad = Asb[st & 1];
        u16* const Bd = Bsb[st & 1];
        if (sopA[p]) { STAGE(A, tile_m, Ad, sc0[p], k0s); STAGE(A, tile_m, Ad, sc1f[p], k0s); }
        else         { STAGE(BT, tile_n, Bd, sc0[p], k0s); STAGE(BT, tile_n, Bd, sc1f[p], k0s); }
      }
      if (q == 3) {
        asm volatile("s_waitcnt vmcnt(6)" ::: "memory");  // next buf's 8 loads landed
        __builtin_amdgcn_sched_barrier(0);
      }
      __builtin_amdgcn_s_barrier();                  // single barrier per phase

      {
        const int pn = p + 1;
        const int qn = pn & 3, bn = (pn >> 2) & 1, as = pn & 1;
#pragma unroll
        for (int kk = 0; kk < 2; ++kk)
#pragma unroll
          for (int mi = 0; mi < 2; ++mi)
            afr2[as][mi][kk] = *(const s8v*)(ap[bn][kk] + (((qn << 1) + mi) << 10));
      }

      __builtin_amdgcn_s_setprio(1);
#pragma unroll
      for (int kk = 0; kk < 2; ++kk)
#pragma unroll
        for (int mi = 0; mi < 2; ++mi)
#pragma unroll
          for (int n = 0; n < 4; ++n)
            acc[q * 2 + mi][n] =
                __builtin_amdgcn_mfma_f32_16x16x32_bf16(afr2[p & 1][mi][kk], bfr[kk][n],
                                                        acc[q * 2 + mi][n], 0, 0, 0);
      __builtin_amdgcn_s_setprio(0);

      if (q == 3) {
        const int bn = ((p + 1) >> 2) & 1;
#pragma unroll
        for (int kk = 0; kk < 2; ++kk)
#pragma unroll
          for (int n = 0; n < 4; ++n)
            bfr[kk][n] = *(const s8v*)(bp[bn][kk] + (n << 10));
      }
    }
  }

  // ---- epilogue: drain in-flight gload_lds from ALL waves, then reuse LDS ----
  asm volatile("s_waitcnt vmcnt(0)" ::: "memory");
  __builtin_amdgcn_s_barrier();

  if (mode == 0) {
    const int selb = tile_n >> 11;
    const int dbase = tile_n & 2047;
    float bias[4];
#pragma unroll
    for (int n = 0; n < 4; ++n) {
      int d = dbase + wn + (n << 4) + l15;
      bias[n] = (selb == 0) ? b_in[d] : (selb == 1) ? (b_dec[d] + dbias[d]) : b_gate[d];
    }
#pragma unroll
    for (int m = 0; m < 8; ++m)
#pragma unroll
      for (int n = 0; n < 4; ++n)
#pragma unroll
        for (int r = 0; r < 4; ++r) {
          int lrow = wm + (m << 4) + (lhi << 2) + r;
          int lcol = wn + (n << 4) + l15;
          float z = acc[m][n][r] + bias[n];
          float v = (selb == 0) ? z * sigm(z) : sigm(z);
          smem[(lrow << 8) + (((lcol >> 3) ^ (lrow & 7)) << 3) + (lcol & 7)] = f2bf(v);
        }
    __builtin_amdgcn_s_barrier();
    u16* const dst = (selb == 0) ? o_inp : (selb == 1) ? o_dec : o_gate;
    const int rr = tid >> 5, sl = tid & 31;
#pragma unroll
    for (int pass = 0; pass < 16; ++pass) {
      int row = (pass << 4) + rr;
      u16x8 v = *(const u16x8*)(smem + (row << 8) + ((sl ^ (row & 7)) << 3));
      *(u16x8*)(dst + (size_t)(tile_m + row) * D_ + dbase + (sl << 3)) = v;
    }
  } else {
    float* const Tf = (float*)smem;
    f4 bo = *(const f4*)(b_out + tile_n + (lane << 2));
#pragma unroll
    for (int sw = 0; sw < 2; ++sw) {
      if (sw) __builtin_amdgcn_s_barrier();
      if ((wm >> 7) == sw) {
#pragma unroll
        for (int m = 0; m < 8; ++m)
#pragma unroll
          for (int n = 0; n < 4; ++n)
#pragma unroll
            for (int r = 0; r < 4; ++r) {
              int lrow = (m << 4) + (lhi << 2) + r;      // 0..127 within sweep
              int lcol = wn + (n << 4) + l15;
              Tf[(lrow << 8) + (((lcol >> 2) ^ (lrow & 7)) << 2) + (lcol & 3)] = acc[m][n][r];
            }
      }
      __builtin_amdgcn_s_barrier();
#pragma unroll
      for (int pass = 0; pass < 16; ++pass) {
        int lrow = (pass << 3) + wave;
        f4 v = *(const f4*)(Tf + (lrow << 8) + ((lane ^ (lrow & 7)) << 2));
        v[0] += bo[0]; v[1] += bo[1]; v[2] += bo[2]; v[3] += bo[3];
        *(f4*)(o_f + (size_t)(tile_m + (sw << 7) + lrow) * D_ + tile_n + (lane << 2)) = v;
      }
    }
  }
}

// ---------------- scan pass 1: per-chunk (prod-decay, zero-init state) ----------------
__global__ void k_scan1(const u16* __restrict__ dec, const u16* __restrict__ inp,
                        float* __restrict__ chA, float* __restrict__ chB) {
  int b = blockIdx.x / CCH, c = blockIdx.x % CCH;
  int d0 = threadIdx.x * 8;
  const u16* dp = dec + ((size_t)b * S_ + c * LCH) * D_ + d0;
  const u16* ip = inp + ((size_t)b * S_ + c * LCH) * D_ + d0;
  float Aa[8], st[8];
#pragma unroll
  for (int i = 0; i < 8; ++i) { Aa[i] = 1.0f; st[i] = 0.0f; }
#pragma unroll 4
  for (int j = 0; j < LCH; ++j) {
    u16x8 dv = *(const u16x8*)(dp + (size_t)j * D_);
    u16x8 iv = *(const u16x8*)(ip + (size_t)j * D_);
#pragma unroll
    for (int i = 0; i < 8; ++i) {
      float dd = bf2f(dv[i]), ii = bf2f(iv[i]);
      Aa[i] *= dd;
      st[i] = dd * st[i] + (1.0f - dd) * ii;
    }
  }
  size_t o = ((size_t)b * CCH + c) * D_ + d0;
#pragma unroll
  for (int i = 0; i < 8; ++i) { chA[o + i] = Aa[i]; chB[o + i] = st[i]; }
}

// ---------------- scan pass 2a: compose 16 chunks -> superchunk (sA, sB) ------
__global__ void k_scan2a(const float* __restrict__ chA, const float* __restrict__ chB,
                         float* __restrict__ sA, float* __restrict__ sB) {
  int gid = blockIdx.x * 256 + threadIdx.x;
  int d = gid & (D_ - 1);
  int s = (gid >> 11) & (SCH - 1);
  int b = gid >> 14;
  float Aa = 1.0f, Bb = 0.0f;
  for (int c = 0; c < SCL; ++c) {
    size_t o = ((size_t)b * CCH + s * SCL + c) * D_ + d;
    float a = chA[o], bb = chB[o];
    Aa *= a;                  // compose: (a2,b2) o (a1,b1) = (a2*a1, a2*b1 + b2)
    Bb = a * Bb + bb;
  }
  size_t so = ((size_t)b * SCH + s) * D_ + d;
  sA[so] = Aa; sB[so] = Bb;
}

// ---------------- scan pass 2b: prefix over 8 superchunks -> super inits ------
__global__ void k_scan2b(const float* __restrict__ sA, const float* __restrict__ sB,
                         float* __restrict__ sI) {
  int gid = blockIdx.x * 256 + threadIdx.x;      // 8192 = 4*2048
  int d = gid & (D_ - 1);
  int b = gid >> 11;
  float st = 0.0f;
  for (int s = 0; s < SCH; ++s) {
    size_t o = ((size_t)b * SCH + s) * D_ + d;
    sI[o] = st;
    st = sA[o] * st + sB[o];
  }
}

// ---------------- scan pass 2c: within-super prefix over chunks -> ini --------
__global__ void k_scan2c(const float* __restrict__ chA, const float* __restrict__ chB,
                         const float* __restrict__ sI, float* __restrict__ ini) {
  int gid = blockIdx.x * 256 + threadIdx.x;      // 65536 = 4*8*2048
  int d = gid & (D_ - 1);
  int s = (gid >> 11) & (SCH - 1);
  int b = gid >> 14;
  float st = sI[((size_t)b * SCH + s) * D_ + d];
  for (int c = 0; c < SCL; ++c) {
    size_t o = ((size_t)b * CCH + s * SCL + c) * D_ + d;
    ini[o] = st;
    st = chA[o] * st + chB[o];
  }
}

// ---------------- scan pass 3: apply with true init, write y = gate*state ----------------
__global__ void k_scan3(const u16* __restrict__ dec, const u16* __restrict__ inp,
                        const u16* __restrict__ gat, const float* __restrict__ ini,
                        u16* __restrict__ y) {
  int b = blockIdx.x / CCH, c = blockIdx.x % CCH;
  int d0 = threadIdx.x * 8;
  size_t ib = ((size_t)b * CCH + c) * D_ + d0;
  float st[8];
#pragma unroll
  for (int i = 0; i < 8; ++i) st[i] = ini[ib + i];
  size_t base = ((size_t)b * S_ + c * LCH) * D_ + d0;
#pragma unroll 4
  for (int j = 0; j < LCH; ++j) {
    size_t o = base + (size_t)j * D_;
    u16x8 dv = *(const u16x8*)(dec + o);
    u16x8 iv = *(const u16x8*)(inp + o);
    u16x8 gv = *(const u16x8*)(gat + o);
    u16x8 yv;
#pragma unroll
    for (int i = 0; i < 8; ++i) {
      float dd = bf2f(dv[i]), ii = bf2f(iv[i]);
      st[i] = dd * st[i] + (1.0f - dd) * ii;
      yv[i] = f2bf(bf2f(gv[i]) * st[i]);
    }
    *(u16x8*)(y + o) = yv;
  }
}

extern "C" void kernel_launch(void* const* d_in, const int* in_sizes, int n_in,
                              void* d_out, int out_size, void* d_ws, size_t ws_size,
                              hipStream_t stream) {
  (void)in_sizes; (void)n_in; (void)out_size; (void)ws_size;
  const float* x      = (const float*)d_in[0];
  const float* W_in   = (const float*)d_in[1];
  const float* b_in   = (const float*)d_in[2];
  const float* W_dec  = (const float*)d_in[3];
  const float* b_dec  = (const float*)d_in[4];
  const float* W_gate = (const float*)d_in[5];
  const float* b_gate = (const float*)d_in[6];
  const float* W_out  = (const float*)d_in[7];
  const float* b_out  = (const float*)d_in[8];
  const float* dbias  = (const float*)d_in[9];
  float* out = (float*)d_out;

  char* ws = (char*)d_ws;
  u16*   xb  = (u16*)(ws);                    // 64 MiB (reused as y)
  u16*   w3t = (u16*)(ws + 67108864ull);      // 24 MiB
  u16*   wot = (u16*)(ws + 92274688ull);      //  8 MiB
  u16*   inp = (u16*)(ws + 100663296ull);     // 64 MiB
  u16*   dec = (u16*)(ws + 167772160ull);     // 64 MiB
  u16*   gat = (u16*)(ws + 234881024ull);     // 64 MiB
  float* chA = (float*)(ws + 301989888ull);   // 4 MiB
  float* chB = (float*)(ws + 306184192ull);   // 4 MiB
  float* ini = (float*)(ws + 310378496ull);   // 4 MiB
  float* sA  = (float*)(ws + 314572800ull);   // 256 KiB
  float* sB  = (float*)(ws + 314834944ull);   // 256 KiB
  float* sI  = (float*)(ws + 315097088ull);   // 256 KiB
  u16*   y   = xb;

  hipFuncSetAttribute((const void*)k_gemm256,
                      hipFuncAttributeMaxDynamicSharedMemorySize, 131072);

  k_cvt<<<2048, 256, 0, stream>>>(x, xb, 8388608);
  k_tcvt4<<<dim3(64, 64, 4), 256, 0, stream>>>(W_in, W_dec, W_gate, W_out, w3t, wot);

  k_gemm256<<<(M_ / 256) * (N3_ / 256), 512, 131072, stream>>>(
      xb, w3t, N3_, 0, inp, dec, gat, b_in, b_dec, b_gate, dbias, nullptr, nullptr);

  k_scan1<<<B_ * CCH, 256, 0, stream>>>(dec, inp, chA, chB);
  k_scan2a<<<256, 256, 0, stream>>>(chA, chB, sA, sB);
  k_scan2b<<<32, 256, 0, stream>>>(sA, sB, sI);
  k_scan2c<<<256, 256, 0, stream>>>(chA, chB, sI, ini);
  k_scan3<<<B_ * CCH, 256, 0, stream>>>(dec, inp, gat, ini, y);

  k_gemm256<<<(M_ / 256) * (D_ / 256), 512, 131072, stream>>>(
      y, wot, D_, 1, nullptr, nullptr, nullptr, nullptr, nullptr, nullptr, nullptr,
      out, b_out);
}